// Round 2
// baseline (359.800 us; speedup 1.0000x reference)
//
#include <hip/hip_runtime.h>

#define BLK 256
#define EPT 2
#define ELEMS (BLK * EPT)          // 512 elements per block
#define WFLOATS (ELEMS * 8)        // 4096 floats = 16 KB weight staging

// Weights LDS layout: logical weight-flat index f (= local_elem*8 + j) is stored
// at physical p = (f - 1) mod 4096, with a quad-level XOR swizzle. The -1 shift
// makes the (base misaligned by 3 floats) global weights region readable as
// aligned float4 quads [S+1+4q .. S+4+4q] from physical quads q = 0..1023;
// the head float (S) and 3-float tail land together in quad 1023 via wraparound.
// The quad XOR spreads staging writes across bank groups.
__device__ __forceinline__ int swz_q(int q) { return q ^ ((q >> 4) & 7); }
__device__ __forceinline__ int swz(int p)  { return (swz_q(p >> 2) << 2) | (p & 3); }

__global__ __launch_bounds__(BLK, 8) void fp4_kernel(
    const float* __restrict__ x,
    const float* __restrict__ delta_raw,
    const float* __restrict__ bounds_base,
    const float* __restrict__ values_table,
    float* __restrict__ out, long long N)
{
    const int tid = threadIdx.x;
    const long long base = (long long)blockIdx.x * ELEMS;
    const long long g0 = base + 2 * tid;

    __shared__ float s_vals[8];
    __shared__ __align__(16) float s_w[WFLOATS];

    if (tid < 8) s_vals[tid] = values_table[tid];

    // wave-uniform scalars; force into SGPR to keep VGPRs <= 64 (8 waves/SIMD)
    float ht = 0.5f * tanhf(delta_raw[0]);
    ht = __int_as_float(__builtin_amdgcn_readfirstlane(__float_as_int(ht)));
    const float C = 14.426950408889634f;        // (1/TAU) * log2(e)
    float sb[7], cb[7];
#pragma unroll
    for (int j = 0; j < 7; ++j) { sb[j] = bounds_base[j] + ht; cb[j] = sb[j] * C; }
    float vt[8];
#pragma unroll
    for (int k = 0; k < 8; ++k) vt[k] = values_table[k];

    __syncthreads();

    const float2 xv = *reinterpret_cast<const float2*>(x + g0);
    const float xe[EPT] = {xv.x, xv.y};

    // per-32-elem amax: local max of 2, butterfly over the 16-lane group.
    // fmax is exactly associative/commutative -> bit-identical to reference order.
    float a = fmaxf(fabsf(xe[0]), fabsf(xe[1]));
    a = fmaxf(a, __shfl_xor(a, 1));
    a = fmaxf(a, __shfl_xor(a, 2));
    a = fmaxf(a, __shfl_xor(a, 4));
    a = fmaxf(a, __shfl_xor(a, 8));

    const float descale = a / 6.0f;                         // exact div (ref-match)
    const float e = ceilf(fmaxf(log2f(descale), -127.0f));  // libm log2 (ref-match)
    const int ie = (int)e;
    const float inv_scale = __int_as_float((127 - ie) << 23);     // 2^-e exact
    const float scale = (ie == -127) ? __int_as_float(0x00400000) // 2^-127 subnormal
                                     : __int_as_float((ie + 127) << 23);

    float ys[EPT], cd[EPT];

#pragma unroll
    for (int i = 0; i < EPT; ++i) {
        const float xs = xe[i] * inv_scale;   // exact: power-of-two multiply
        const float xa = fabsf(xs);

        int ord = 0;
#pragma unroll
        for (int j = 0; j < 7; ++j) ord += (xa > sb[j]) ? 1 : 0;   // exact compares

        const float xac = xa * C;
        float p[7];
#pragma unroll
        for (int j = 0; j < 7; ++j) {
            const float ex = exp2f(cb[j] - xac);        // exp((sb-xa)/tau) via v_exp
            p[j] = __builtin_amdgcn_rcpf(1.0f + ex);    // sigmoid
        }

        float w[8];
        w[0] = 1.0f - p[0];
#pragma unroll
        for (int j = 1; j < 7; ++j) w[j] = p[j - 1] - p[j];
        w[7] = p[6];

        float sum = 0.0f;
#pragma unroll
        for (int k = 0; k < 8; ++k) { w[k] = fmaxf(w[k], 0.0f); sum += w[k]; }
        const float inv = __builtin_amdgcn_rcpf(sum + 1e-8f);

        float abs_soft = 0.0f;
#pragma unroll
        for (int k = 0; k < 8; ++k) { w[k] *= inv; abs_soft += w[k] * vt[k]; }

        const float abs_hard = s_vals[ord];                      // LDS dynamic index
        const float abs_mix = abs_soft + (abs_hard - abs_soft);  // faithful ST expr
        ys[i] = ((xs >= 0.0f) ? abs_mix : -abs_mix) * scale;
        cd[i] = (float)(((xs < 0.0f) ? 8 : 0) | ord);

        // stage weights at p = 8*el + j - 1 (mod 4096), swizzled
        const int el = 2 * tid + i;
        s_w[swz(((el << 3) - 1) & (WFLOATS - 1))] = w[0];           // j=0
        *reinterpret_cast<float4*>(&s_w[swz_q(el << 1) << 2]) =     // j=1..4
            make_float4(w[1], w[2], w[3], w[4]);
        const int qb = swz_q((el << 1) | 1) << 2;                   // j=5..7
        *reinterpret_cast<float2*>(&s_w[qb]) = make_float2(w[5], w[6]);
        s_w[qb + 2] = w[7];
    }

    // y / codes: aligned float2 vector stores (g0 even)
    *reinterpret_cast<float2*>(out + g0)     = make_float2(ys[0], ys[1]);
    *reinterpret_cast<float2*>(out + N + g0) = make_float2(cd[0], cd[1]);
    if ((tid & 15) == 0) out[2 * N + (g0 >> 5)] = e + 127.0f;
    if (blockIdx.x == 0 && tid < 7) {
        float v = sb[0];                       // select chain: no scratch from
#pragma unroll
        for (int j = 1; j < 7; ++j) v = (tid == j) ? sb[j] : v;   // dynamic SGPR idx
        out[2 * N + (N >> 5) + tid] = v;
    }

    __syncthreads();

    // weights writeback: 4 aligned float4 stores/thread, 1 KB contiguous per
    // wave-instr; LDS b128 reads conflict-free (contiguous quads under swizzle).
    // S = global float index of this block's weights region, S ≡ 3 (mod 4).
    const long long S = 2 * N + (N >> 5) + 7 + (long long)blockIdx.x * WFLOATS;
#pragma unroll
    for (int k = 0; k < 4; ++k) {
        const int q = tid + (k << 8);
        const float4 v = *reinterpret_cast<const float4*>(&s_w[swz_q(q) << 2]);
        if (q != 1023) {
            *reinterpret_cast<float4*>(out + (S + 1 + 4 * (long long)q)) = v;
        } else {   // wrap quad: logical floats {4093,4094,4095, 0}
            out[S + 4093] = v.x;
            out[S + 4094] = v.y;
            out[S + 4095] = v.z;
            out[S]        = v.w;
        }
    }
}

extern "C" void kernel_launch(void* const* d_in, const int* in_sizes, int n_in,
                              void* d_out, int out_size, void* d_ws, size_t ws_size,
                              hipStream_t stream) {
    const float* x      = (const float*)d_in[0];
    const float* delta  = (const float*)d_in[1];
    const float* bounds = (const float*)d_in[2];
    const float* vals   = (const float*)d_in[3];
    float* out = (float*)d_out;
    const long long N = (long long)in_sizes[0];   // 8388608 = 2^23
    const int nblocks = (int)(N / ELEMS);
    fp4_kernel<<<nblocks, BLK, 0, stream>>>(x, delta, bounds, vals, out, N);
}